// Round 8
// baseline (257.912 us; speedup 1.0000x reference)
//
#include <hip/hip_runtime.h>

// CausalSelfAttention: x[4,2048,1024] fp32 -> out fp32
// Pipeline (all bf16 MFMA, fp32 accum):
//  1) cvt x -> bf16            2) transpose+cvt W_attn & W_proj -> bf16 [N][K]
//  3) gemm_bt + bias -> Q (pre-scaled by 0.125*log2e) [b,h,s,d], K [b,h,s,d],
//     V TRANSPOSED [b,h,d,s]  (all bf16)
//  4) flash attention: 128 q-rows/block, XCD head-affinity swizzle, fixed-max
//     softmax (P=2^s), DOUBLE-BUFFERED K/V direct-to-LDS with raw s_barrier +
//     manual vmcnt (loads in flight across the barrier, AITER-style).
//  5) gemm_bt(Y, W_projT) + bias -> out fp32
// MFMA 16x16x32 bf16 layouts (HW-verified per guide):
//   A: a[j] = A[m=lane&15][k=quad*8+j]  (quad=lane>>4)
//   B: b[j] = B[k=quad*8+j][n=lane&15]
//   C/D: c[i] = D[row=quad*4+i][col=lane&15]
//
// REGISTER BUDGET NOTE (R4/R5): gemm needs ~120 unified regs. min-waves=6
// forced a ~85-reg cap -> accumulator spill -> 923 MB WRITE_SIZE, 3x slower.
// Keep gemm at min-waves=3. launch_bounds cannot RAISE occupancy, only cap regs.
// R7 diagnosis: attn FETCH 257->25 MB (XCD affinity works); now stall-bound
// (Mfma 18 + VALU 37 = 55% busy) on the per-tile vmcnt(0)+barrier drain.
// R8: dbuf + raw s_barrier + vmcnt(4) prefetch-across-barrier, 3 blocks/CU.

#define BATCH 4
#define SEQ   2048
#define EMB   1024
#define NH    16
#define HD    64

typedef __bf16 bf16;
typedef __bf16 bf16x8 __attribute__((ext_vector_type(8)));
typedef float  f32x4  __attribute__((ext_vector_type(4)));

// direct global->LDS 16B copy: LDS dest is wave-uniform base + lane*16
__device__ __forceinline__ void ld_lds16(const void* g, void* l) {
  __builtin_amdgcn_global_load_lds(
      (const __attribute__((address_space(1))) void*)g,
      (__attribute__((address_space(3))) void*)l, 16, 0, 0);
}

// ---------------- convert fp32 -> bf16 ----------------
__global__ void cvt_f32_bf16(const float* __restrict__ in, bf16* __restrict__ out, int n) {
  int i = (blockIdx.x * blockDim.x + threadIdx.x) * 4;
  if (i + 3 < n) {
    float4 v = *(const float4*)(in + i);
    bf16 o0 = (bf16)v.x, o1 = (bf16)v.y, o2 = (bf16)v.z, o3 = (bf16)v.w;
    out[i] = o0; out[i+1] = o1; out[i+2] = o2; out[i+3] = o3;
  }
}

// ---------------- transpose + convert both weights (one launch) ----------------
__global__ void transpose_cvt2(const float* __restrict__ Wa, const float* __restrict__ Wp,
                               bf16* __restrict__ WaT, bf16* __restrict__ WpT) {
  __shared__ float tile[32][33];
  int bx = blockIdx.x;
  const float* W; bf16* WT; int N;
  if (bx < 96) { W = Wa; WT = WaT; N = 3072; }
  else         { W = Wp; WT = WpT; N = 1024; bx -= 96; }
  int n0 = bx * 32, k0 = blockIdx.y * 32;
  int tx = threadIdx.x & 31, ty = threadIdx.x >> 5;
#pragma unroll
  for (int r = 0; r < 4; r++) {
    int k = k0 + ty + r * 8;
    tile[ty + r * 8][tx] = W[(long)k * N + n0 + tx];
  }
  __syncthreads();
#pragma unroll
  for (int r = 0; r < 4; r++) {
    int n = n0 + ty + r * 8;
    WT[(long)n * EMB + k0 + tx] = (bf16)tile[tx][ty + r * 8];
  }
}

// ---------------- GEMM: A[M][K] bf16 x Bt[N][K] bf16 + bias ----------------
// 128 x BNT tile, BK=64, direct-to-LDS staging, XOR source swizzle,
// XCD-L2 block swizzle.  (dbuf deliberately NOT applied: m99/m131/m139 show
// it neutral for this GEMM shape.)
#define QSCALE 0.18033688f   // (1/8) * log2(e)

template <int BNT>
__global__ __launch_bounds__(256, 3) void gemm_bt(
    const bf16* __restrict__ A, const bf16* __restrict__ Bt,
    const float* __restrict__ bias, int Kdim, int Ncols, int mode,
    bf16* __restrict__ q, bf16* __restrict__ k, bf16* __restrict__ v,
    float* __restrict__ out)
{
  constexpr int NF = BNT / 32;               // n-fragments per wave
  __shared__ __align__(16) bf16 Al[128 * 64];
  __shared__ __align__(16) bf16 Bl[BNT * 64];
  int lin = blockIdx.x;
  int xcd = lin & 7, s = lin >> 3;
  int bx = s >> 3, by = xcd * 8 + (s & 7);
  int m0 = by * 128;
  int n0 = bx * BNT;
  int t = threadIdx.x;
  int wave = t >> 6, lane = t & 63;
  int l15 = lane & 15, quad = lane >> 4;
  int wm = (wave & 1) * 64, wn = (wave >> 1) * (BNT / 2);

  f32x4 acc[4][NF] = {};

  for (int kt = 0; kt < Kdim; kt += 64) {
    __syncthreads();
#pragma unroll
    for (int it = 0; it < 4; ++it) {         // A: 128 rows x 8 units
      int c = it * 256 + t;
      int row = c >> 3, u = c & 7;
      ld_lds16(&A[(long)(m0 + row) * Kdim + kt + ((u ^ (row & 7)) * 8)],
               &Al[(it * 256 + wave * 64) * 8]);
    }
#pragma unroll
    for (int it = 0; it < BNT / 32; ++it) {  // B: BNT rows x 8 units
      int c = it * 256 + t;
      int row = c >> 3, u = c & 7;
      ld_lds16(&Bt[(long)(n0 + row) * Kdim + kt + ((u ^ (row & 7)) * 8)],
               &Bl[(it * 256 + wave * 64) * 8]);
    }
    __syncthreads();
#pragma unroll
    for (int ks = 0; ks < 2; ++ks) {
      bf16x8 af[4], bfr[NF];
#pragma unroll
      for (int i = 0; i < 4; ++i) {
        int r = wm + i * 16 + l15;
        af[i] = *(const bf16x8*)(&Al[r * 64 + (((ks * 4 + quad) ^ (r & 7)) * 8)]);
      }
#pragma unroll
      for (int i = 0; i < NF; ++i) {
        int r = wn + i * 16 + l15;
        bfr[i] = *(const bf16x8*)(&Bl[r * 64 + (((ks * 4 + quad) ^ (r & 7)) * 8)]);
      }
#pragma unroll
      for (int mi = 0; mi < 4; ++mi)
#pragma unroll
        for (int ni = 0; ni < NF; ++ni)
          acc[mi][ni] = __builtin_amdgcn_mfma_f32_16x16x32_bf16(af[mi], bfr[ni], acc[mi][ni], 0, 0, 0);
    }
  }

  // epilogue
#pragma unroll
  for (int mi = 0; mi < 4; ++mi) {
#pragma unroll
    for (int ni = 0; ni < NF; ++ni) {
      int gcol = n0 + wn + ni * 16 + l15;
      float bv = bias[gcol];
#pragma unroll
      for (int i = 0; i < 4; ++i) {
        int grow = m0 + wm + mi * 16 + quad * 4 + i;
        float val = acc[mi][ni][i] + bv;
        if (mode == 0) {
          int which = gcol >> 10, e = gcol & 1023;
          int h = e >> 6, d = e & 63;
          int b = grow >> 11, ss = grow & 2047;
          if (which == 0) {
            q[(((long)b * NH + h) * SEQ + ss) * HD + d] = (bf16)(val * QSCALE);
          } else if (which == 1) {
            k[(((long)b * NH + h) * SEQ + ss) * HD + d] = (bf16)val;
          } else {
            v[(((long)b * NH + h) * HD + d) * SEQ + ss] = (bf16)val;  // V^T
          }
        } else {
          out[(long)grow * Ncols + gcol] = val;
        }
      }
    }
  }
}

// ---------------- flash attention ----------------
// 1D grid 512 blocks; block 256 = 4 waves x 32 q-rows = 128-row strip.
// head = (L&7) + 8*((L>>3)&7) -> all 8 blocks of a head share L%8 (one XCD's
// L2 holds the head's 512 KB K/V). strip st = L>>6; runs strips st and 15-st.
// K/V double-buffered: stage tile kt+1, wait vmcnt(4) (kt's 4 loads done,
// prefetch stays in flight), RAW s_barrier (no compiler vmcnt(0) drain),
// compute, raw s_barrier (buffer-reuse protection).
#define LDP 72   // P row stride (elems): conflict-free, 16B-aligned

__global__ __launch_bounds__(256, 3) void attn(
    const bf16* __restrict__ Q, const bf16* __restrict__ K,
    const bf16* __restrict__ Vt, bf16* __restrict__ Y)
{
  __shared__ __align__(16) bf16 Kl[2][64 * 64];     // 2 x 8 KB
  __shared__ __align__(16) bf16 Vl[2][64 * 64];     // 2 x 8 KB
  __shared__ __align__(16) bf16 Pl[4][32 * LDP];    // 18 KB, per-wave
  int L = blockIdx.x;
  int a = L >> 3;
  int hd = (L & 7) + 8 * (a & 7);
  int st = a >> 3;
  int b = hd >> 4, h = hd & 15;
  const bf16* Qp  = Q  + (((long)b * NH + h) * SEQ) * HD;
  const bf16* Kp  = K  + (((long)b * NH + h) * SEQ) * HD;
  const bf16* Vtp = Vt + (((long)b * NH + h) * HD) * SEQ;
  int t = threadIdx.x, wave = t >> 6, lane = t & 63;
  int l15 = lane & 15, quad = lane >> 4;
  // staging coords (4 ld_lds16 per thread per tile)
  int srow = t >> 3, su = t & 7;

#pragma unroll 1
  for (int pass = 0; pass < 2; ++pass) {
    int q0 = (pass == 0) ? st * 128 : (SEQ - 128) - st * 128;
    int wq0 = q0 + wave * 32;

    // Q fragments: m-frag m covers rows wq0+m*16 .. +15; k split 0/32
    bf16x8 qf[2][2];
#pragma unroll
    for (int m = 0; m < 2; ++m) {
      const bf16* qrow = Qp + (long)(wq0 + m * 16 + l15) * HD + quad * 8;
      qf[m][0] = *(const bf16x8*)(qrow);
      qf[m][1] = *(const bf16x8*)(qrow + 32);
    }
    float lrow[2][4] = {};
    f32x4 oacc[2][4] = {};

    int ntiles = q0 / 64 + 2;     // block's 128 rows need tiles through q0+127

    // stage tile 0 into buffer 0 (2 K + 2 V ld_lds16 per thread)
    {
      int k0 = 0;
#pragma unroll
      for (int it = 0; it < 2; ++it) {
        int row = it * 32 + srow;
        ld_lds16(&Kp[(long)(k0 + row) * HD + ((su ^ (row & 7)) * 8)],
                 &Kl[0][(it * 256 + wave * 64) * 8]);
        ld_lds16(&Vtp[(long)row * SEQ + k0 + ((su ^ (row & 7)) * 8)],
                 &Vl[0][(it * 256 + wave * 64) * 8]);
      }
    }

#pragma unroll 1
    for (int kt = 0; kt < ntiles; ++kt) {
      int k0 = kt * 64;
      if (kt + 1 < ntiles) {
        int k0n = k0 + 64, nb = (kt + 1) & 1;
#pragma unroll
        for (int it = 0; it < 2; ++it) {
          int row = it * 32 + srow;
          ld_lds16(&Kp[(long)(k0n + row) * HD + ((su ^ (row & 7)) * 8)],
                   &Kl[nb][(it * 256 + wave * 64) * 8]);
          ld_lds16(&Vtp[(long)row * SEQ + k0n + ((su ^ (row & 7)) * 8)],
                   &Vl[nb][(it * 256 + wave * 64) * 8]);
        }
        // 8 outstanding: wait until only the 4 newest (prefetch) remain
        asm volatile("s_waitcnt vmcnt(4)" ::: "memory");
      } else {
        asm volatile("s_waitcnt vmcnt(0)" ::: "memory");
      }
      asm volatile("s_barrier" ::: "memory");   // raw: no vmcnt(0) drain

      const bf16* Kc = Kl[kt & 1];
      const bf16* Vc = Vl[kt & 1];
      if (k0 <= wq0 + 31) {     // wave has unmasked rows in this tile
        // scores: S[32q x 64k]; kfr register-shared across both m-frags
        f32x4 sc[2][4] = {};
#pragma unroll
        for (int kk = 0; kk < 2; ++kk) {
#pragma unroll
          for (int ni = 0; ni < 4; ++ni) {
            int r = ni * 16 + l15, u = kk * 4 + quad;
            bf16x8 kfr = *(const bf16x8*)(&Kc[r * 64 + ((u ^ (r & 7)) * 8)]);
            sc[0][ni] = __builtin_amdgcn_mfma_f32_16x16x32_bf16(qf[0][kk], kfr, sc[0][ni], 0, 0, 0);
            sc[1][ni] = __builtin_amdgcn_mfma_f32_16x16x32_bf16(qf[1][kk], kfr, sc[1][ni], 0, 0, 0);
          }
        }

        bool full = (k0 + 63 <= wq0);   // wave-uniform (min row = wq0)
#pragma unroll
        for (int m = 0; m < 2; ++m) {
#pragma unroll
          for (int i = 0; i < 4; ++i) {
            int qr = wq0 + m * 16 + quad * 4 + i;
            float e[4];
#pragma unroll
            for (int ni = 0; ni < 4; ++ni) {
              float x = sc[m][ni][i];
              if (!full) x = (k0 + ni * 16 + l15 <= qr) ? x : -1e30f;
              e[ni] = __builtin_amdgcn_exp2f(x);
            }
            lrow[m][i] += (e[0] + e[1]) + (e[2] + e[3]);
            int prow = (m * 16 + quad * 4 + i) * LDP;
#pragma unroll
            for (int ni = 0; ni < 4; ++ni)
              Pl[wave][prow + ni * 16 + l15] = (bf16)e[ni];
          }
        }
        asm volatile("s_waitcnt lgkmcnt(0)" ::: "memory");
        // PV: P[32x64] @ V[64x64]; vf register-shared across both m-frags
#pragma unroll
        for (int kk = 0; kk < 2; ++kk) {
          int kbase = kk * 32 + quad * 8;
          bf16x8 pf0 = *(const bf16x8*)(&Pl[wave][(l15) * LDP + kbase]);
          bf16x8 pf1 = *(const bf16x8*)(&Pl[wave][(16 + l15) * LDP + kbase]);
#pragma unroll
          for (int ni = 0; ni < 4; ++ni) {
            int dd = ni * 16 + l15, u = kk * 4 + quad;
            bf16x8 vf = *(const bf16x8*)(&Vc[dd * 64 + ((u ^ (dd & 7)) * 8)]);
            oacc[0][ni] = __builtin_amdgcn_mfma_f32_16x16x32_bf16(pf0, vf, oacc[0][ni], 0, 0, 0);
            oacc[1][ni] = __builtin_amdgcn_mfma_f32_16x16x32_bf16(pf1, vf, oacc[1][ni], 0, 0, 0);
          }
        }
      }
      asm volatile("s_barrier" ::: "memory");   // protect buf before overwrite
    }
    // epilogue: reduce l across the 16-lane column groups, write Y bf16
#pragma unroll
    for (int m = 0; m < 2; ++m) {
#pragma unroll
      for (int i = 0; i < 4; ++i) {
        float rs = lrow[m][i];
#pragma unroll
        for (int off = 8; off; off >>= 1) rs += __shfl_xor(rs, off, 16);
        float inv = 1.0f / rs;
        int qr = wq0 + m * 16 + quad * 4 + i;
        bf16* dst = Y + ((long)(b * SEQ + qr)) * EMB + h * HD;
#pragma unroll
        for (int ni = 0; ni < 4; ++ni)
          dst[ni * 16 + l15] = (bf16)(oacc[m][ni][i] * inv);
      }
    }
  }
}

extern "C" void kernel_launch(void* const* d_in, const int* in_sizes, int n_in,
                              void* d_out, int out_size, void* d_ws, size_t ws_size,
                              hipStream_t stream) {
  const float* x      = (const float*)d_in[0];
  const float* W_attn = (const float*)d_in[1];
  const float* b_attn = (const float*)d_in[2];
  const float* W_proj = (const float*)d_in[3];
  const float* b_proj = (const float*)d_in[4];
  float* out = (float*)d_out;
  char* ws = (char*)d_ws;
  bf16* xb  = (bf16*)(ws);                 // 16.78 MB
  bf16* WaT = (bf16*)(ws + 16777216);      //  6.29 MB
  bf16* WpT = (bf16*)(ws + 23068672);      //  2.10 MB
  bf16* Qb  = (bf16*)(ws + 25165824);      // 16.78 MB (pre-scaled)
  bf16* Kb  = (bf16*)(ws + 41943040);      // 16.78 MB
  bf16* Vtb = (bf16*)(ws + 58720256);      // 16.78 MB (transposed [b,h,d,s])
  bf16* Yb  = (bf16*)(ws + 75497472);      // 16.78 MB

  cvt_f32_bf16<<<8192, 256, 0, stream>>>(x, xb, BATCH * SEQ * EMB);
  transpose_cvt2<<<dim3(128, 32), 256, 0, stream>>>(W_attn, W_proj, WaT, WpT);
  gemm_bt<128><<<1536, 256, 0, stream>>>(xb, WaT, b_attn, EMB, 3 * EMB, 0,
                                         Qb, Kb, Vtb, nullptr);
  attn<<<512, 256, 0, stream>>>(Qb, Kb, Vtb, Yb);
  gemm_bt<64><<<1024, 256, 0, stream>>>(Yb, WpT, b_proj, EMB, EMB, 1,
                                        nullptr, nullptr, nullptr, out);
}